// Round 12
// baseline (160.311 us; speedup 1.0000x reference)
//
#include <hip/hip_runtime.h>
#include <stdint.h>

#define Bz 4
#define Tz 2048
#define Cz 1024
#define NHz 16
#define DHz 64
#define Mz (Bz*Tz)

typedef unsigned short u16;
typedef __attribute__((ext_vector_type(8))) short short8;
typedef __attribute__((ext_vector_type(8))) unsigned short ushort8v;
typedef __attribute__((ext_vector_type(4))) unsigned short u16x4;
typedef __attribute__((ext_vector_type(4))) float f32x4;
typedef __attribute__((ext_vector_type(2))) unsigned int uint2v;

__device__ __forceinline__ float bf2f(u16 u){
  union { unsigned int i; float f; } v; v.i = ((unsigned int)u) << 16; return v.f;
}
__device__ __forceinline__ u16 f2bf(float f){
  union { float f; unsigned int i; } v; v.f = f;
  unsigned int r = v.i + 0x7FFFu + ((v.i >> 16) & 1u);
  return (u16)(r >> 16);
}

// ---------------- pre-pass kernels ----------------

__global__ void k_cast_bf16(const float* __restrict__ in, u16* __restrict__ out, int n4){
  int i = blockIdx.x*256 + threadIdx.x;
  if (i >= n4) return;
  float4 v = ((const float4*)in)[i];
  u16x4 o;
  o[0] = f2bf(v.x); o[1] = f2bf(v.y); o[2] = f2bf(v.z); o[3] = f2bf(v.w);
  *(u16x4*)(out + (size_t)i*4) = o;
}

__global__ void k_transpose_cast(const float* __restrict__ W, u16* __restrict__ Wt, int K, int N){
  __shared__ float tile[32][33];
  int n0 = blockIdx.x*32, k0 = blockIdx.y*32;
  int tx = threadIdx.x, ty = threadIdx.y;
  #pragma unroll
  for (int i = 0; i < 32; i += 8)
    tile[ty+i][tx] = W[(size_t)(k0+ty+i)*N + n0 + tx];
  __syncthreads();
  #pragma unroll
  for (int i = 0; i < 32; i += 8)
    Wt[(size_t)(n0+ty+i)*K + k0 + tx] = f2bf(tile[tx][ty+i]);
}

__global__ void k_rope_tables(float* __restrict__ cosT, float* __restrict__ sinT){
  int idx = blockIdx.x*256 + threadIdx.x;   // 2048*32 entries
  int t = idx >> 5, i = idx & 31;
  float theta = exp2f(-(float)i * (13.287712379549449f / 32.0f)); // 10000^(-i/32)
  float ang = (float)t * theta;
  cosT[idx] = cosf(ang);
  sinT[idx] = sinf(ang);
}

// ---------------- GEMM-1: m97-style 128x128, BK=32, 16KB single-buffered ----------------
// 4 waves (2x2 of 64x64). 16KB LDS -> ~6 blocks/CU co-resident; implicit
// cross-block overlap (m114) hides the per-tile barrier drains. Natural 2-D
// grid (bm fastest: per-XCD A-residue stays in L2; round-9 FETCH evidence).
// Light 4-way both-sides XOR swizzle; setprio; fused RoPE/vT epilogue.
template<int Nn, int Kk, bool ROPE>
__global__ void k_gemm97(const u16* __restrict__ A, const u16* __restrict__ Bt,
                         void* __restrict__ Cout, u16* __restrict__ vTout,
                         const float* __restrict__ cosT, const float* __restrict__ sinT){
  __shared__ u16 Asub[128*32];
  __shared__ u16 Bsub[128*32];
  const int bm = blockIdx.x, bn = blockIdx.y;
  const int tid = threadIdx.x, lane = tid & 63, w = tid >> 6;
  const int g = lane >> 4, r = lane & 15;
  const int wm = (w >> 1)*64, wn = (w & 1)*64;
  f32x4 acc[4][4] = {};

  const int srow4 = lane >> 2;                 // row within 16-row chunk
  const int sslot = (lane & 3) ^ (srow4 & 3);  // pre-swizzled 16B source slot
  const u16* arow = A  + (size_t)(bm*128)*Kk;
  const u16* brow = Bt + (size_t)(bn*128)*Kk;

  int a_ofs[4], b_ofs[4];
  #pragma unroll
  for (int i = 0; i < 4; ++i){
    a_ofs[i] = (wm + i*16 + r)*64 + ((g ^ (r & 3)) << 4);
    b_ofs[i] = (wn + i*16 + r)*64 + ((g ^ (r & 3)) << 4);
  }

  for (int k0 = 0; k0 < Kk; k0 += 32){
    #pragma unroll
    for (int ic = 0; ic < 2; ++ic){
      int ch = w*2 + ic;
      int row = ch*16 + srow4;
      __builtin_amdgcn_global_load_lds(
        (const __attribute__((address_space(1))) unsigned int*)(arow + (size_t)row*Kk + k0 + sslot*8),
        (__attribute__((address_space(3))) unsigned int*)(Asub + ch*512 + lane*8), 16, 0, 0);
      __builtin_amdgcn_global_load_lds(
        (const __attribute__((address_space(1))) unsigned int*)(brow + (size_t)row*Kk + k0 + sslot*8),
        (__attribute__((address_space(3))) unsigned int*)(Bsub + ch*512 + lane*8), 16, 0, 0);
    }
    __syncthreads();
    short8 af[4], bfr[4];
    #pragma unroll
    for (int i = 0; i < 4; ++i){
      af[i]  = *(const short8*)((const char*)Asub + a_ofs[i]);
      bfr[i] = *(const short8*)((const char*)Bsub + b_ofs[i]);
    }
    __builtin_amdgcn_s_setprio(1);
    #pragma unroll
    for (int i = 0; i < 4; ++i)
      #pragma unroll
      for (int j = 0; j < 4; ++j)
        acc[i][j] = __builtin_amdgcn_mfma_f32_16x16x32_bf16(af[i], bfr[j], acc[i][j], 0, 0, 0);
    __builtin_amdgcn_s_setprio(0);
    __syncthreads();
  }

  // ---------------- epilogue ----------------
  const int nbase = bn*128 + wn;
  if (ROPE && nbase >= 2048){
    // v plane -> vT[(b*16+h)*64 + d][2048]
    const int b = bm >> 4;
    const int h = (nbase >> 6) & 15;
    #pragma unroll
    for (int ri = 0; ri < 4; ++ri){
      const int m0 = bm*128 + wm + ri*16 + 4*g;
      const int t0 = m0 & (Tz-1);
      #pragma unroll
      for (int cj = 0; cj < 4; ++cj){
        const int d = cj*16 + r;
        u16x4 o;
        #pragma unroll
        for (int jj = 0; jj < 4; ++jj) o[jj] = f2bf(acc[ri][cj][jj]);
        *(u16x4*)(vTout + ((size_t)((b*16 + h)*64 + d))*2048 + t0) = o;
      }
    }
  } else if (ROPE){
    const float qs = (nbase < 1024) ? 0.18033688011112042f : 1.0f;  // 0.125*log2e on q
    #pragma unroll
    for (int ri = 0; ri < 4; ++ri)
      #pragma unroll
      for (int jj = 0; jj < 4; ++jj){
        const int m = bm*128 + wm + ri*16 + 4*g + jj;
        const int t = m & (Tz-1);
        #pragma unroll
        for (int cj = 0; cj < 2; ++cj){
          const int ch = cj*16 + r;
          float cv = cosT[t*32 + ch];
          float sv = sinT[t*32 + ch];
          float lo = acc[ri][cj][jj], hi = acc[ri][cj+2][jj];
          ((u16*)Cout)[(size_t)m*Nn + nbase + ch]      = f2bf((lo*cv - hi*sv)*qs);
          ((u16*)Cout)[(size_t)m*Nn + nbase + ch + 32] = f2bf((hi*cv + lo*sv)*qs);
        }
      }
  } else {
    #pragma unroll
    for (int ri = 0; ri < 4; ++ri)
      #pragma unroll
      for (int cj = 0; cj < 4; ++cj)
        #pragma unroll
        for (int jj = 0; jj < 4; ++jj){
          const size_t m = bm*128 + wm + ri*16 + 4*g + jj;
          const size_t n = (size_t)nbase + cj*16 + r;
          ((float*)Cout)[m*Nn + n] = acc[ri][cj][jj];
        }
  }
}

// ---------------- GEMM-2: 128x128, BK=64, dbuf (round-9 k_gemmdb) ----------------
#define GLDS(src, dstE) __builtin_amdgcn_global_load_lds( \
    (const __attribute__((address_space(1))) unsigned int*)(src), \
    (__attribute__((address_space(3))) unsigned int*)((u16*)lds + (dstE)), 16, 0, 0)

template<int Nn, int Kk>
__global__ __launch_bounds__(256, 4) void k_gemmdb(const u16* __restrict__ A, const u16* __restrict__ Bt,
                        float* __restrict__ Cout){
  __shared__ u16 lds[2][16384];           // [buf][ A 128x64 | B 128x64 ]  = 64 KB
  constexpr int NT = Kk/64;
  const int bm = blockIdx.x, bn = blockIdx.y;
  const int tid = threadIdx.x, lane = tid & 63, w = tid >> 6;
  const int wm = (w >> 1)*64, wn = (w & 1)*64;
  const int g = lane >> 4, r = lane & 15;

  const int srow8 = lane >> 3;
  const int sslot = (lane & 7) ^ srow8;   // pre-swizzled source slot (involution)
  const u16* asrc = A  + (size_t)(bm*128 + w*32 + srow8)*Kk + sslot*8;
  const u16* bsrc = Bt + (size_t)(bn*128 + w*32 + srow8)*Kk + sslot*8;
  const int dA = w*2048 + lane*8;
  const int dB = 8192 + w*2048 + lane*8;

  int a_off[4][2], b_off[4][2];
  #pragma unroll
  for (int i = 0; i < 4; ++i)
    #pragma unroll
    for (int kc = 0; kc < 2; ++kc){
      int row = wm + i*16 + r;
      a_off[i][kc] = (row*128 + kc*64 + g*16) ^ ((r & 7) << 4);
      int rowb = wn + i*16 + r;
      b_off[i][kc] = 16384 + ((rowb*128 + kc*64 + g*16) ^ ((r & 7) << 4));
    }

  f32x4 acc[4][4] = {};

#define STG(t, bi) do{ \
    const size_t ko_ = (size_t)(t)*64; \
    const int be_ = (bi)*16384; \
    GLDS(asrc + ko_,                 be_ + dA);        \
    GLDS(asrc + ko_ +  8*(size_t)Kk, be_ + dA + 512);  \
    GLDS(asrc + ko_ + 16*(size_t)Kk, be_ + dA + 1024); \
    GLDS(asrc + ko_ + 24*(size_t)Kk, be_ + dA + 1536); \
    GLDS(bsrc + ko_,                 be_ + dB);        \
    GLDS(bsrc + ko_ +  8*(size_t)Kk, be_ + dB + 512);  \
    GLDS(bsrc + ko_ + 16*(size_t)Kk, be_ + dB + 1024); \
    GLDS(bsrc + ko_ + 24*(size_t)Kk, be_ + dB + 1536); \
  }while(0)

  STG(0, 0);
  asm volatile("s_waitcnt vmcnt(0)" ::: "memory");
  __builtin_amdgcn_s_barrier();

  int buf = 0;
  #pragma unroll 1
  for (int t = 0; t < NT; ++t){
    if (t + 1 < NT) STG(t+1, buf^1);
    const char* Lb = (const char*)lds + buf*32768;
    short8 af[4][2], bf[4][2];
    #pragma unroll
    for (int i = 0; i < 4; ++i)
      #pragma unroll
      for (int kc = 0; kc < 2; ++kc){
        af[i][kc] = *(const short8*)(Lb + a_off[i][kc]);
        bf[i][kc] = *(const short8*)(Lb + b_off[i][kc]);
      }
    __builtin_amdgcn_s_setprio(1);
    #pragma unroll
    for (int i = 0; i < 4; ++i)
      #pragma unroll
      for (int j = 0; j < 4; ++j){
        acc[i][j] = __builtin_amdgcn_mfma_f32_16x16x32_bf16(af[i][0], bf[j][0], acc[i][j], 0,0,0);
        acc[i][j] = __builtin_amdgcn_mfma_f32_16x16x32_bf16(af[i][1], bf[j][1], acc[i][j], 0,0,0);
      }
    __builtin_amdgcn_s_setprio(0);
    if (t + 1 < NT){
      asm volatile("s_waitcnt vmcnt(0)" ::: "memory");
      __builtin_amdgcn_s_barrier();
      buf ^= 1;
    }
  }
#undef STG

  const int nbase = bn*128 + wn;
  #pragma unroll
  for (int ri = 0; ri < 4; ++ri)
    #pragma unroll
    for (int cj = 0; cj < 4; ++cj)
      #pragma unroll
      for (int jj = 0; jj < 4; ++jj){
        const size_t m = bm*128 + wm + ri*16 + 4*g + jj;
        const size_t n = (size_t)nbase + cj*16 + r;
        Cout[m*Nn + n] = acc[ri][cj][jj];
      }
}

// ---------------- flash attention v7 (unchanged from round 11) ----------------
__global__ __launch_bounds__(512) void k_attn2(const u16* __restrict__ qkv,
                                               const u16* __restrict__ vT,
                                               u16* __restrict__ att){
  __shared__ u16 K_lds[2*4096];
  __shared__ u16 V_lds[2*4096];
  __shared__ u16 P_lds[8*16*72];

  const int bh = blockIdx.x;           // bh fastest -> K/V L2 locality per XCD
  const int b = bh >> 4, h = bh & 15;
  const int qt = 15 - blockIdx.y;      // heavy blocks first
  const int tid = threadIdx.x;
  const int w = tid >> 6;
  const int lane = tid & 63;
  const int g = lane >> 4;
  const int ql = lane & 15;
  u16* Pw = P_lds + w*16*72;

  const int srow  = lane >> 3;
  const int sslot = (lane & 7) ^ srow;
  const u16* ksrc = qkv + ((size_t)(b*Tz + 8*w + srow))*3072 + 1024 + h*64 + sslot*8;
  const u16* vsrc = vT  + ((size_t)bh*64 + 8*w + srow)*2048 + sslot*8;
  u16* kdst = K_lds + w*512 + lane*8;
  u16* vdst = V_lds + w*512 + lane*8;

  short8 ones;
  #pragma unroll
  for (int i = 0; i < 8; ++i) ones[i] = (short)0x3F80;   // bf16 1.0

  int fofs[4][2];
  #pragma unroll
  for (int t = 0; t < 4; ++t){
    int row = 16*t + ql;
    fofs[t][0] = (row*128 + 16*g)      ^ ((row & 7) << 4);
    fofs[t][1] = (row*128 + 64 + 16*g) ^ ((row & 7) << 4);
  }

  const int qr0w = qt*128 + w*16;
  const int nt = 2*qt + 2;

  const u16* qsrc = qkv + (size_t)(b*Tz + qr0w + ql)*3072 + h*64;
  short8 qf0 = *(const short8*)(qsrc + g*8);
  short8 qf1 = *(const short8*)(qsrc + 32 + g*8);

  f32x4 acc[4] = {{0,0,0,0},{0,0,0,0},{0,0,0,0},{0,0,0,0}};
  f32x4 accl = {0,0,0,0};   // row-sum of P via ones-MFMA

  __builtin_amdgcn_global_load_lds(
    (const __attribute__((address_space(1))) unsigned int*)(ksrc),
    (__attribute__((address_space(3))) unsigned int*)(kdst), 16, 0, 0);
  __builtin_amdgcn_global_load_lds(
    (const __attribute__((address_space(1))) unsigned int*)(vsrc),
    (__attribute__((address_space(3))) unsigned int*)(vdst), 16, 0, 0);
  __syncthreads();

  #pragma unroll 2
  for (int kt = 0; kt < nt; ++kt){
    const int buf = kt & 1;
    if (kt + 1 < nt){
      __builtin_amdgcn_global_load_lds(
        (const __attribute__((address_space(1))) unsigned int*)(ksrc + (size_t)(kt+1)*64*3072),
        (__attribute__((address_space(3))) unsigned int*)(kdst + (buf^1)*4096), 16, 0, 0);
      __builtin_amdgcn_global_load_lds(
        (const __attribute__((address_space(1))) unsigned int*)(vsrc + (kt+1)*64),
        (__attribute__((address_space(3))) unsigned int*)(vdst + (buf^1)*4096), 16, 0, 0);
    }
    const char* Kb = (const char*)(K_lds + buf*4096);
    const char* Vb = (const char*)(V_lds + buf*4096);
    const int kv0 = kt*64;

    f32x4 st[4];
    __builtin_amdgcn_s_setprio(1);
    #pragma unroll
    for (int t = 0; t < 4; ++t){
      short8 kf0 = *(const short8*)(Kb + fofs[t][0]);
      short8 kf1 = *(const short8*)(Kb + fofs[t][1]);
      f32x4 z = {0,0,0,0};
      z = __builtin_amdgcn_mfma_f32_16x16x32_bf16(kf0, qf0, z, 0, 0, 0);
      z = __builtin_amdgcn_mfma_f32_16x16x32_bf16(kf1, qf1, z, 0, 0, 0);
      st[t] = z;
    }
    __builtin_amdgcn_s_setprio(0);

    if (kv0 + 63 > qr0w){
      const int qg = qr0w + ql;
      #pragma unroll
      for (int t = 0; t < 4; ++t)
        #pragma unroll
        for (int j = 0; j < 4; ++j)
          if (kv0 + 16*t + 4*g + j > qg) st[t][j] = -1e30f;
    }

    #pragma unroll
    for (int t = 0; t < 4; ++t){
      float p0, p1, p2, p3;
      asm("v_exp_f32 %0, %1" : "=v"(p0) : "v"(st[t][0]));
      asm("v_exp_f32 %0, %1" : "=v"(p1) : "v"(st[t][1]));
      asm("v_exp_f32 %0, %1" : "=v"(p2) : "v"(st[t][2]));
      asm("v_exp_f32 %0, %1" : "=v"(p3) : "v"(st[t][3]));
      unsigned int lov, hiv;
      asm("v_cvt_pk_bf16_f32 %0, %1, %2" : "=v"(lov) : "v"(p0), "v"(p1));
      asm("v_cvt_pk_bf16_f32 %0, %1, %2" : "=v"(hiv) : "v"(p2), "v"(p3));
      uint2v pv; pv[0] = lov; pv[1] = hiv;
      *(uint2v*)((char*)Pw + ql*144 + (16*t + 4*g)*2) = pv;
    }

    short8 pf0 = *(const short8*)((char*)Pw + ql*144 + 16*g);
    short8 pf1 = *(const short8*)((char*)Pw + ql*144 + 64 + 16*g);
    __builtin_amdgcn_s_setprio(1);
    accl = __builtin_amdgcn_mfma_f32_16x16x32_bf16(pf0, ones, accl, 0, 0, 0);
    accl = __builtin_amdgcn_mfma_f32_16x16x32_bf16(pf1, ones, accl, 0, 0, 0);
    #pragma unroll
    for (int dt = 0; dt < 4; ++dt){
      short8 vf0 = *(const short8*)(Vb + fofs[dt][0]);
      short8 vf1 = *(const short8*)(Vb + fofs[dt][1]);
      acc[dt] = __builtin_amdgcn_mfma_f32_16x16x32_bf16(pf0, vf0, acc[dt], 0, 0, 0);
      acc[dt] = __builtin_amdgcn_mfma_f32_16x16x32_bf16(pf1, vf1, acc[dt], 0, 0, 0);
    }
    __builtin_amdgcn_s_setprio(0);
    __syncthreads();
  }

  float lj[4];
  #pragma unroll
  for (int j = 0; j < 4; ++j) lj[j] = 1.0f / accl[j];
  #pragma unroll
  for (int dt = 0; dt < 4; ++dt)
    #pragma unroll
    for (int j = 0; j < 4; ++j)
      att[(size_t)(b*Tz + qr0w + 4*g + j)*Cz + h*64 + dt*16 + ql] = f2bf(acc[dt][j]*lj[j]);
}

// ---------------- launcher ----------------

extern "C" void kernel_launch(void* const* d_in, const int* in_sizes, int n_in,
                              void* d_out, int out_size, void* d_ws, size_t ws_size,
                              hipStream_t stream){
  const float* x     = (const float*)d_in[0];
  const float* Wqkv  = (const float*)d_in[1];
  const float* Wproj = (const float*)d_in[2];
  float* out = (float*)d_out;
  char* ws = (char*)d_ws;

  u16*  xb   = (u16*)(ws);                      // x bf16; reused as attn output
  u16*  wqt  = (u16*)(ws + 16777216);
  u16*  wpt  = (u16*)(ws + 23068672);
  u16*  qkv  = (u16*)(ws + 25165824);           // q,k planes (v diverted to vT)
  u16*  vTr  = (u16*)(ws + 75497472);           // V^T [bh*64+d][2048]
  float* cosT = (float*)(ws + 92274688);
  float* sinT = (float*)(ws + 92536832);

  k_cast_bf16<<<Mz*Cz/4/256, 256, 0, stream>>>(x, xb, Mz*Cz/4);
  k_transpose_cast<<<dim3(3072/32, 1024/32), dim3(32,8), 0, stream>>>(Wqkv, wqt, 1024, 3072);
  k_transpose_cast<<<dim3(1024/32, 1024/32), dim3(32,8), 0, stream>>>(Wproj, wpt, 1024, 1024);
  k_rope_tables<<<Tz*32/256, 256, 0, stream>>>(cosT, sinT);

  k_gemm97<3072, 1024, true><<<dim3(Mz/128, 3072/128), 256, 0, stream>>>(
      xb, wqt, qkv, vTr, cosT, sinT);
  k_attn2<<<dim3(Bz*NHz, 16), 512, 0, stream>>>(qkv, vTr, xb);
  k_gemmdb<1024, 1024><<<dim3(Mz/128, 1024/128), 256, 0, stream>>>(
      xb, wpt, out);
}

// Round 13
// 146.839 us; speedup vs baseline: 1.0917x; 1.0917x over previous
//
#include <hip/hip_runtime.h>
#include <stdint.h>

#define Bz 4
#define Tz 2048
#define Cz 1024
#define NHz 16
#define DHz 64
#define Mz (Bz*Tz)

typedef unsigned short u16;
typedef __attribute__((ext_vector_type(8))) short short8;
typedef __attribute__((ext_vector_type(8))) unsigned short ushort8v;
typedef __attribute__((ext_vector_type(4))) unsigned short u16x4;
typedef __attribute__((ext_vector_type(4))) float f32x4;
typedef __attribute__((ext_vector_type(2))) unsigned int uint2v;

__device__ __forceinline__ float bf2f(u16 u){
  union { unsigned int i; float f; } v; v.i = ((unsigned int)u) << 16; return v.f;
}
__device__ __forceinline__ u16 f2bf(float f){
  union { float f; unsigned int i; } v; v.f = f;
  unsigned int r = v.i + 0x7FFFu + ((v.i >> 16) & 1u);
  return (u16)(r >> 16);
}

// ---------------- fused pre-pass ----------------
// One launch, block-range dispatch (branch is block-uniform):
//   [0, 8192)            : cast x f32 -> bf16 (float4/lane)
//   [8192, 11264)        : transpose+cast Wqkv (1024x3072 -> 3072x1024)
//   [11264, 12288)       : transpose+cast Wproj (1024x1024)
//   [12288, 12544)       : RoPE cos/sin tables (2048 x 32)
__global__ void k_prep(const float* __restrict__ x,     u16* __restrict__ xb,
                       const float* __restrict__ Wqkv,  u16* __restrict__ wqt,
                       const float* __restrict__ Wproj, u16* __restrict__ wpt,
                       float* __restrict__ cosT, float* __restrict__ sinT){
  __shared__ float tile[32][33];
  const int blk = blockIdx.x;
  const int tid = threadIdx.x;
  if (blk < 8192){
    int i = blk*256 + tid;
    float4 v = ((const float4*)x)[i];
    u16x4 o;
    o[0] = f2bf(v.x); o[1] = f2bf(v.y); o[2] = f2bf(v.z); o[3] = f2bf(v.w);
    *(u16x4*)(xb + (size_t)i*4) = o;
  } else if (blk < 12288){
    const float* W; u16* Wt; int K, N, bx, by;
    if (blk < 11264){ int b2 = blk - 8192;  W = Wqkv;  Wt = wqt; K = 1024; N = 3072; bx = b2 % 96; by = b2 / 96; }
    else            { int b2 = blk - 11264; W = Wproj; Wt = wpt; K = 1024; N = 1024; bx = b2 % 32; by = b2 / 32; }
    const int n0 = bx*32, k0 = by*32;
    const int tx = tid & 31, ty = tid >> 5;
    #pragma unroll
    for (int i = 0; i < 32; i += 8)
      tile[ty+i][tx] = W[(size_t)(k0+ty+i)*N + n0 + tx];
    __syncthreads();
    #pragma unroll
    for (int i = 0; i < 32; i += 8)
      Wt[(size_t)(n0+ty+i)*K + k0 + tx] = f2bf(tile[tx][ty+i]);
  } else {
    int idx = (blk - 12288)*256 + tid;      // 2048*32 entries
    int t = idx >> 5, i = idx & 31;
    float theta = exp2f(-(float)i * (13.287712379549449f / 32.0f)); // 10000^(-i/32)
    float ang = (float)t * theta;
    cosT[idx] = cosf(ang);
    sinT[idx] = sinf(ang);
  }
}

// ---------------- GEMM: 128x128, BK=64, 4 waves of 64x64, double-buffered ----------------
#define GLDS(src, dstE) __builtin_amdgcn_global_load_lds( \
    (const __attribute__((address_space(1))) unsigned int*)(src), \
    (__attribute__((address_space(3))) unsigned int*)((u16*)lds + (dstE)), 16, 0, 0)

template<int Nn, int Kk, bool ROPE>
__global__ __launch_bounds__(256, 4) void k_gemmdb(const u16* __restrict__ A, const u16* __restrict__ Bt,
                        void* __restrict__ Cout, u16* __restrict__ vTout,
                        const float* __restrict__ cosT, const float* __restrict__ sinT){
  __shared__ u16 lds[2][16384];           // [buf][ A 128x64 | B 128x64 ]  = 64 KB
  constexpr int NT = Kk/64;
  const int bm = blockIdx.x, bn = blockIdx.y;
  const int tid = threadIdx.x, lane = tid & 63, w = tid >> 6;
  const int wm = (w >> 1)*64, wn = (w & 1)*64;
  const int g = lane >> 4, r = lane & 15;

  const int srow8 = lane >> 3;
  const int sslot = (lane & 7) ^ srow8;   // pre-swizzled source slot (involution)
  const u16* asrc = A  + (size_t)(bm*128 + w*32 + srow8)*Kk + sslot*8;
  const u16* bsrc = Bt + (size_t)(bn*128 + w*32 + srow8)*Kk + sslot*8;
  const int dA = w*2048 + lane*8;
  const int dB = 8192 + w*2048 + lane*8;

  int a_off[4][2], b_off[4][2];
  #pragma unroll
  for (int i = 0; i < 4; ++i)
    #pragma unroll
    for (int kc = 0; kc < 2; ++kc){
      int row = wm + i*16 + r;
      a_off[i][kc] = (row*128 + kc*64 + g*16) ^ ((r & 7) << 4);
      int rowb = wn + i*16 + r;
      b_off[i][kc] = 16384 + ((rowb*128 + kc*64 + g*16) ^ ((r & 7) << 4));
    }

  f32x4 acc[4][4] = {};

#define STG(t, bi) do{ \
    const size_t ko_ = (size_t)(t)*64; \
    const int be_ = (bi)*16384; \
    GLDS(asrc + ko_,                 be_ + dA);        \
    GLDS(asrc + ko_ +  8*(size_t)Kk, be_ + dA + 512);  \
    GLDS(asrc + ko_ + 16*(size_t)Kk, be_ + dA + 1024); \
    GLDS(asrc + ko_ + 24*(size_t)Kk, be_ + dA + 1536); \
    GLDS(bsrc + ko_,                 be_ + dB);        \
    GLDS(bsrc + ko_ +  8*(size_t)Kk, be_ + dB + 512);  \
    GLDS(bsrc + ko_ + 16*(size_t)Kk, be_ + dB + 1024); \
    GLDS(bsrc + ko_ + 24*(size_t)Kk, be_ + dB + 1536); \
  }while(0)

  STG(0, 0);
  asm volatile("s_waitcnt vmcnt(0)" ::: "memory");
  __builtin_amdgcn_s_barrier();

  int buf = 0;
  #pragma unroll 1
  for (int t = 0; t < NT; ++t){
    if (t + 1 < NT) STG(t+1, buf^1);
    const char* Lb = (const char*)lds + buf*32768;
    short8 af[4][2], bf[4][2];
    #pragma unroll
    for (int i = 0; i < 4; ++i)
      #pragma unroll
      for (int kc = 0; kc < 2; ++kc){
        af[i][kc] = *(const short8*)(Lb + a_off[i][kc]);
        bf[i][kc] = *(const short8*)(Lb + b_off[i][kc]);
      }
    __builtin_amdgcn_s_setprio(1);
    #pragma unroll
    for (int i = 0; i < 4; ++i)
      #pragma unroll
      for (int j = 0; j < 4; ++j){
        acc[i][j] = __builtin_amdgcn_mfma_f32_16x16x32_bf16(af[i][0], bf[j][0], acc[i][j], 0,0,0);
        acc[i][j] = __builtin_amdgcn_mfma_f32_16x16x32_bf16(af[i][1], bf[j][1], acc[i][j], 0,0,0);
      }
    __builtin_amdgcn_s_setprio(0);
    if (t + 1 < NT){
      asm volatile("s_waitcnt vmcnt(0)" ::: "memory");
      __builtin_amdgcn_s_barrier();
      buf ^= 1;
    }
  }
#undef STG

  // ---------------- epilogue ----------------
  const int nbase = bn*128 + wn;
  if (ROPE && nbase >= 2048){
    const int b = bm >> 4;
    const int h = (nbase >> 6) & 15;
    #pragma unroll
    for (int ri = 0; ri < 4; ++ri){
      const int m0 = bm*128 + wm + ri*16 + 4*g;
      const int t0 = m0 & (Tz-1);
      #pragma unroll
      for (int cj = 0; cj < 4; ++cj){
        const int d = cj*16 + r;
        u16x4 o;
        #pragma unroll
        for (int jj = 0; jj < 4; ++jj) o[jj] = f2bf(acc[ri][cj][jj]);
        *(u16x4*)(vTout + ((size_t)((b*16 + h)*64 + d))*2048 + t0) = o;
      }
    }
  } else if (ROPE){
    const float qs = (nbase < 1024) ? 0.18033688011112042f : 1.0f;  // 0.125*log2e on q
    #pragma unroll
    for (int ri = 0; ri < 4; ++ri)
      #pragma unroll
      for (int jj = 0; jj < 4; ++jj){
        const int m = bm*128 + wm + ri*16 + 4*g + jj;
        const int t = m & (Tz-1);
        #pragma unroll
        for (int cj = 0; cj < 2; ++cj){
          const int ch = cj*16 + r;
          float cv = cosT[t*32 + ch];
          float sv = sinT[t*32 + ch];
          float lo = acc[ri][cj][jj], hi = acc[ri][cj+2][jj];
          ((u16*)Cout)[(size_t)m*Nn + nbase + ch]      = f2bf((lo*cv - hi*sv)*qs);
          ((u16*)Cout)[(size_t)m*Nn + nbase + ch + 32] = f2bf((hi*cv + lo*sv)*qs);
        }
      }
  } else {
    #pragma unroll
    for (int ri = 0; ri < 4; ++ri)
      #pragma unroll
      for (int cj = 0; cj < 4; ++cj)
        #pragma unroll
        for (int jj = 0; jj < 4; ++jj){
          const size_t m = bm*128 + wm + ri*16 + 4*g + jj;
          const size_t n = (size_t)nbase + cj*16 + r;
          ((float*)Cout)[m*Nn + n] = acc[ri][cj][jj];
        }
  }
}

// ---------------- flash attention v7 (round-11) ----------------
__global__ __launch_bounds__(512) void k_attn2(const u16* __restrict__ qkv,
                                               const u16* __restrict__ vT,
                                               u16* __restrict__ att){
  __shared__ u16 K_lds[2*4096];
  __shared__ u16 V_lds[2*4096];
  __shared__ u16 P_lds[8*16*72];

  const int bh = blockIdx.x;           // bh fastest -> K/V L2 locality per XCD
  const int b = bh >> 4, h = bh & 15;
  const int qt = 15 - blockIdx.y;      // heavy blocks first
  const int tid = threadIdx.x;
  const int w = tid >> 6;
  const int lane = tid & 63;
  const int g = lane >> 4;
  const int ql = lane & 15;
  u16* Pw = P_lds + w*16*72;

  const int srow  = lane >> 3;
  const int sslot = (lane & 7) ^ srow;
  const u16* ksrc = qkv + ((size_t)(b*Tz + 8*w + srow))*3072 + 1024 + h*64 + sslot*8;
  const u16* vsrc = vT  + ((size_t)bh*64 + 8*w + srow)*2048 + sslot*8;
  u16* kdst = K_lds + w*512 + lane*8;
  u16* vdst = V_lds + w*512 + lane*8;

  short8 ones;
  #pragma unroll
  for (int i = 0; i < 8; ++i) ones[i] = (short)0x3F80;   // bf16 1.0

  int fofs[4][2];
  #pragma unroll
  for (int t = 0; t < 4; ++t){
    int row = 16*t + ql;
    fofs[t][0] = (row*128 + 16*g)      ^ ((row & 7) << 4);
    fofs[t][1] = (row*128 + 64 + 16*g) ^ ((row & 7) << 4);
  }

  const int qr0w = qt*128 + w*16;
  const int nt = 2*qt + 2;

  const u16* qsrc = qkv + (size_t)(b*Tz + qr0w + ql)*3072 + h*64;
  short8 qf0 = *(const short8*)(qsrc + g*8);
  short8 qf1 = *(const short8*)(qsrc + 32 + g*8);

  f32x4 acc[4] = {{0,0,0,0},{0,0,0,0},{0,0,0,0},{0,0,0,0}};
  f32x4 accl = {0,0,0,0};   // row-sum of P via ones-MFMA

  __builtin_amdgcn_global_load_lds(
    (const __attribute__((address_space(1))) unsigned int*)(ksrc),
    (__attribute__((address_space(3))) unsigned int*)(kdst), 16, 0, 0);
  __builtin_amdgcn_global_load_lds(
    (const __attribute__((address_space(1))) unsigned int*)(vsrc),
    (__attribute__((address_space(3))) unsigned int*)(vdst), 16, 0, 0);
  __syncthreads();

  #pragma unroll 2
  for (int kt = 0; kt < nt; ++kt){
    const int buf = kt & 1;
    if (kt + 1 < nt){
      __builtin_amdgcn_global_load_lds(
        (const __attribute__((address_space(1))) unsigned int*)(ksrc + (size_t)(kt+1)*64*3072),
        (__attribute__((address_space(3))) unsigned int*)(kdst + (buf^1)*4096), 16, 0, 0);
      __builtin_amdgcn_global_load_lds(
        (const __attribute__((address_space(1))) unsigned int*)(vsrc + (kt+1)*64),
        (__attribute__((address_space(3))) unsigned int*)(vdst + (buf^1)*4096), 16, 0, 0);
    }
    const char* Kb = (const char*)(K_lds + buf*4096);
    const char* Vb = (const char*)(V_lds + buf*4096);
    const int kv0 = kt*64;

    f32x4 st[4];
    __builtin_amdgcn_s_setprio(1);
    #pragma unroll
    for (int t = 0; t < 4; ++t){
      short8 kf0 = *(const short8*)(Kb + fofs[t][0]);
      short8 kf1 = *(const short8*)(Kb + fofs[t][1]);
      f32x4 z = {0,0,0,0};
      z = __builtin_amdgcn_mfma_f32_16x16x32_bf16(kf0, qf0, z, 0, 0, 0);
      z = __builtin_amdgcn_mfma_f32_16x16x32_bf16(kf1, qf1, z, 0, 0, 0);
      st[t] = z;
    }
    __builtin_amdgcn_s_setprio(0);

    if (kv0 + 63 > qr0w){
      const int qg = qr0w + ql;
      #pragma unroll
      for (int t = 0; t < 4; ++t)
        #pragma unroll
        for (int j = 0; j < 4; ++j)
          if (kv0 + 16*t + 4*g + j > qg) st[t][j] = -1e30f;
    }

    #pragma unroll
    for (int t = 0; t < 4; ++t){
      float p0, p1, p2, p3;
      asm("v_exp_f32 %0, %1" : "=v"(p0) : "v"(st[t][0]));
      asm("v_exp_f32 %0, %1" : "=v"(p1) : "v"(st[t][1]));
      asm("v_exp_f32 %0, %1" : "=v"(p2) : "v"(st[t][2]));
      asm("v_exp_f32 %0, %1" : "=v"(p3) : "v"(st[t][3]));
      unsigned int lov, hiv;
      asm("v_cvt_pk_bf16_f32 %0, %1, %2" : "=v"(lov) : "v"(p0), "v"(p1));
      asm("v_cvt_pk_bf16_f32 %0, %1, %2" : "=v"(hiv) : "v"(p2), "v"(p3));
      uint2v pv; pv[0] = lov; pv[1] = hiv;
      *(uint2v*)((char*)Pw + ql*144 + (16*t + 4*g)*2) = pv;
    }

    short8 pf0 = *(const short8*)((char*)Pw + ql*144 + 16*g);
    short8 pf1 = *(const short8*)((char*)Pw + ql*144 + 64 + 16*g);
    __builtin_amdgcn_s_setprio(1);
    accl = __builtin_amdgcn_mfma_f32_16x16x32_bf16(pf0, ones, accl, 0, 0, 0);
    accl = __builtin_amdgcn_mfma_f32_16x16x32_bf16(pf1, ones, accl, 0, 0, 0);
    #pragma unroll
    for (int dt = 0; dt < 4; ++dt){
      short8 vf0 = *(const short8*)(Vb + fofs[dt][0]);
      short8 vf1 = *(const short8*)(Vb + fofs[dt][1]);
      acc[dt] = __builtin_amdgcn_mfma_f32_16x16x32_bf16(pf0, vf0, acc[dt], 0, 0, 0);
      acc[dt] = __builtin_amdgcn_mfma_f32_16x16x32_bf16(pf1, vf1, acc[dt], 0, 0, 0);
    }
    __builtin_amdgcn_s_setprio(0);
    __syncthreads();
  }

  float lj[4];
  #pragma unroll
  for (int j = 0; j < 4; ++j) lj[j] = 1.0f / accl[j];
  #pragma unroll
  for (int dt = 0; dt < 4; ++dt)
    #pragma unroll
    for (int j = 0; j < 4; ++j)
      att[(size_t)(b*Tz + qr0w + 4*g + j)*Cz + h*64 + dt*16 + ql] = f2bf(acc[dt][j]*lj[j]);
}

// ---------------- launcher ----------------

extern "C" void kernel_launch(void* const* d_in, const int* in_sizes, int n_in,
                              void* d_out, int out_size, void* d_ws, size_t ws_size,
                              hipStream_t stream){
  const float* x     = (const float*)d_in[0];
  const float* Wqkv  = (const float*)d_in[1];
  const float* Wproj = (const float*)d_in[2];
  float* out = (float*)d_out;
  char* ws = (char*)d_ws;

  u16*  xb   = (u16*)(ws);                      // x bf16; reused as attn output
  u16*  wqt  = (u16*)(ws + 16777216);
  u16*  wpt  = (u16*)(ws + 23068672);
  u16*  qkv  = (u16*)(ws + 25165824);           // q,k planes (v diverted to vT)
  u16*  vTr  = (u16*)(ws + 75497472);           // V^T [bh*64+d][2048]
  float* cosT = (float*)(ws + 92274688);
  float* sinT = (float*)(ws + 92536832);

  k_prep<<<12544, 256, 0, stream>>>(x, xb, Wqkv, wqt, Wproj, wpt, cosT, sinT);

  k_gemmdb<3072, 1024, true><<<dim3(Mz/128, 3072/128), 256, 0, stream>>>(
      xb, wqt, qkv, vTr, cosT, sinT);
  k_attn2<<<dim3(Bz*NHz, 16), 512, 0, stream>>>(qkv, vTr, xb);
  k_gemmdb<1024, 1024, false><<<dim3(Mz/128, 1024/128), 256, 0, stream>>>(
      xb, wpt, out, nullptr, nullptr, nullptr);
}